// Round 1
// baseline (523.705 us; speedup 1.0000x reference)
//
#include <hip/hip_runtime.h>

#define B_ 32
#define HH 56
#define WW 56
#define C_ 96
#define E_ 4
#define M_ 384
#define F_ 96
#define P_ 3136
#define EPS 1e-3f

typedef __attribute__((ext_vector_type(8))) __bf16 bf16x8;
typedef __attribute__((ext_vector_type(8))) short short8;
typedef __attribute__((ext_vector_type(4))) float f32x4;
typedef unsigned short u16;

__device__ __forceinline__ float bf2f(u16 s) {
  union { unsigned u; float f; } c;
  c.u = ((unsigned)s) << 16;
  return c.f;
}
__device__ __forceinline__ u16 f2bf(float f) {
  union { float f; unsigned u; } c;
  c.f = f;
  unsigned u = c.u + 0x7FFFu + ((c.u >> 16) & 1u);
  return (u16)(u >> 16);
}

// ---------------- routing: pooled mean -> sigmoid(pooled@Wr+br); also x -> bf16
__global__ __launch_bounds__(384) void k_routing(
    const float* __restrict__ x, const float* __restrict__ Wr,
    const float* __restrict__ br, float* __restrict__ rw, u16* __restrict__ xbf) {
  int b = blockIdx.x;
  int t = threadIdx.x;
  int c = t % C_, s = t / C_;  // s in 0..3
  const float* xb = x + (size_t)b * P_ * C_;
  u16* xbb = xbf + (size_t)b * P_ * C_;
  float sum = 0.f;
  for (int p = s; p < P_; p += 4) {
    float v = xb[(size_t)p * C_ + c];
    sum += v;
    xbb[(size_t)p * C_ + c] = f2bf(v);
  }
  __shared__ float part[4][C_];
  __shared__ float pooled[C_];
  part[s][c] = sum;
  __syncthreads();
  if (t < C_) pooled[t] = (part[0][t] + part[1][t] + part[2][t] + part[3][t]) * (1.f / (float)P_);
  __syncthreads();
  if (t < E_) {
    float acc = br[t];
    for (int cc = 0; cc < C_; ++cc) acc += pooled[cc] * Wr[cc * E_ + t];
    rw[b * E_ + t] = 1.f / (1.f + expf(-acc));
  }
}

// ---------------- combine expand weights: Wk_t[b][m][c] (bf16, BN1-folded), bias1p[b][m]
__global__ __launch_bounds__(384) void k_mkw1(
    const float* __restrict__ Wpw, const float* __restrict__ bpw,
    const float* __restrict__ rw,
    const float* __restrict__ g1, const float* __restrict__ b1,
    const float* __restrict__ m1, const float* __restrict__ v1,
    u16* __restrict__ Wk_t, float* __restrict__ bias1p) {
  int b = blockIdx.x;
  float r0 = rw[b * 4 + 0], r1 = rw[b * 4 + 1], r2 = rw[b * 4 + 2], r3 = rw[b * 4 + 3];
  int m = threadIdx.x;  // 384 threads, one per m
  float s1 = g1[m] * rsqrtf(v1[m] + EPS);
  for (int c = 0; c < C_; ++c) {
    float w = r0 * Wpw[(0 * C_ + c) * M_ + m] + r1 * Wpw[(1 * C_ + c) * M_ + m] +
              r2 * Wpw[(2 * C_ + c) * M_ + m] + r3 * Wpw[(3 * C_ + c) * M_ + m];
    Wk_t[((size_t)b * M_ + m) * C_ + c] = f2bf(w * s1);
  }
  float bias = r0 * bpw[0 * M_ + m] + r1 * bpw[1 * M_ + m] + r2 * bpw[2 * M_ + m] + r3 * bpw[3 * M_ + m];
  bias1p[b * M_ + m] = (bias - m1[m]) * s1 + b1[m];
}

// ---------------- combine depthwise weights: Wdwf_t[b][oct][tap0..8 | 9=bias][8] fp32, BN2-folded
__global__ __launch_bounds__(384) void k_mkdw(
    const float* __restrict__ Wdw, const float* __restrict__ bdw,
    const float* __restrict__ rw,
    const float* __restrict__ g2, const float* __restrict__ b2,
    const float* __restrict__ m2, const float* __restrict__ v2,
    float* __restrict__ Wdwf_t) {
  int b = blockIdx.x;
  float r0 = rw[b * 4 + 0], r1 = rw[b * 4 + 1], r2 = rw[b * 4 + 2], r3 = rw[b * 4 + 3];
  int m = threadIdx.x;  // 384
  int oct = m / 8, q = m % 8;
  float s2 = g2[m] * rsqrtf(v2[m] + EPS);
  float* base = Wdwf_t + (((size_t)b * 48 + oct) * 10) * 8;
  for (int tap = 0; tap < 9; ++tap) {
    float w = r0 * Wdw[(0 * 9 + tap) * M_ + m] + r1 * Wdw[(1 * 9 + tap) * M_ + m] +
              r2 * Wdw[(2 * 9 + tap) * M_ + m] + r3 * Wdw[(3 * 9 + tap) * M_ + m];
    base[tap * 8 + q] = w * s2;
  }
  float bias = r0 * bdw[0 * M_ + m] + r1 * bdw[1 * M_ + m] + r2 * bdw[2 * M_ + m] + r3 * bdw[3 * M_ + m];
  base[9 * 8 + q] = (bias - m2[m]) * s2 + b2[m];
}

// ---------------- combine project weights: Wk2_t[b][f][m] (bf16, BN3-folded), bias3p[b][f]
__global__ __launch_bounds__(384) void k_mkw2(
    const float* __restrict__ Wpwl, const float* __restrict__ bpwl,
    const float* __restrict__ rw,
    const float* __restrict__ g3, const float* __restrict__ b3,
    const float* __restrict__ m3, const float* __restrict__ v3,
    u16* __restrict__ Wk2_t, float* __restrict__ bias3p) {
  int b = blockIdx.x;
  float r0 = rw[b * 4 + 0], r1 = rw[b * 4 + 1], r2 = rw[b * 4 + 2], r3 = rw[b * 4 + 3];
  int f = threadIdx.x % F_, s = threadIdx.x / F_;
  float s3 = g3[f] * rsqrtf(v3[f] + EPS);
  for (int m = s; m < M_; m += 4) {
    float w = r0 * Wpwl[(0 * M_ + m) * F_ + f] + r1 * Wpwl[(1 * M_ + m) * F_ + f] +
              r2 * Wpwl[(2 * M_ + m) * F_ + f] + r3 * Wpwl[(3 * M_ + m) * F_ + f];
    Wk2_t[((size_t)b * F_ + f) * M_ + m] = f2bf(w * s3);
  }
  if (s == 0) {
    float bias = r0 * bpwl[0 * F_ + f] + r1 * bpwl[1 * F_ + f] + r2 * bpwl[2 * F_ + f] + r3 * bpwl[3 * F_ + f];
    bias3p[b * F_ + f] = (bias - m3[f]) * s3 + b3[f];
  }
}

// ---------------- expand GEMM: h1[b][p][m] = relu(x_bf[p][:] @ Wk_t[m][:] + bias1p)  (bf16 out)
__global__ __launch_bounds__(256) void k_expand(
    const u16* __restrict__ xbf, const u16* __restrict__ Wk_t,
    const float* __restrict__ bias1p, u16* __restrict__ h1) {
  __shared__ __align__(16) u16 As[64][104];  // 64 rows x 96 k (+8 pad)
  __shared__ __align__(16) u16 Bs[64][104];  // 64 cols x 96 k
  int b = blockIdx.z, pt = blockIdx.x, nt = blockIdx.y;
  int p0 = pt * 64, n0 = nt * 64;
  int t = threadIdx.x;
  const u16* A = xbf + ((size_t)b * P_ + p0) * C_;
  const u16* Bt = Wk_t + ((size_t)b * M_ + n0) * C_;
#pragma unroll
  for (int j = 0; j < 3; ++j) {
    int ch = t + 256 * j;
    int r = ch / 12, o = (ch % 12) * 8;
    *(short8*)&As[r][o] = *(const short8*)&A[(size_t)r * C_ + o];
    *(short8*)&Bs[r][o] = *(const short8*)&Bt[(size_t)r * C_ + o];
  }
  __syncthreads();
  int lane = t & 63, w = t >> 6;
  int rA = w * 16 + (lane & 15);
  int k0 = (lane >> 4) * 8;
  f32x4 acc[4] = {};
#pragma unroll
  for (int kc = 0; kc < 3; ++kc) {
    bf16x8 a = *(const bf16x8*)&As[rA][kc * 32 + k0];
#pragma unroll
    for (int ct = 0; ct < 4; ++ct) {
      bf16x8 bb = *(const bf16x8*)&Bs[ct * 16 + (lane & 15)][kc * 32 + k0];
      acc[ct] = __builtin_amdgcn_mfma_f32_16x16x32_bf16(a, bb, acc[ct], 0, 0, 0);
    }
  }
  u16* out = h1 + (size_t)b * P_ * M_;
  int rowb = p0 + w * 16 + (lane >> 4) * 4;
#pragma unroll
  for (int ct = 0; ct < 4; ++ct) {
    int m = n0 + ct * 16 + (lane & 15);
    float bias = bias1p[b * M_ + m];
#pragma unroll
    for (int i = 0; i < 4; ++i) {
      float v = fmaxf(acc[ct][i] + bias, 0.f);
      out[(size_t)(rowb + i) * M_ + m] = f2bf(v);
    }
  }
}

// ---------------- depthwise 3x3 (SAME, zero pad) + BN2 + relu, bf16 in/out
__global__ __launch_bounds__(256) void k_dw(
    const u16* __restrict__ h1, const float* __restrict__ Wdwf_t,
    u16* __restrict__ h2) {
  int y = blockIdx.x, b = blockIdx.y;
  const u16* in = h1 + (size_t)b * P_ * M_;
  u16* out = h2 + (size_t)b * P_ * M_;
  const float* wb = Wdwf_t + (size_t)b * 48 * 10 * 8;
  for (int task = threadIdx.x; task < 56 * 48; task += 256) {
    int xw = task / 48, oct = task % 48;
    int mo = oct * 8;
    const float* wo = wb + oct * 80;
    float acc[8];
#pragma unroll
    for (int q = 0; q < 8; ++q) acc[q] = wo[72 + q];  // bias slot
#pragma unroll
    for (int dy = -1; dy <= 1; ++dy) {
      int yy = y + dy;
      if (yy < 0 || yy >= 56) continue;
#pragma unroll
      for (int dx = -1; dx <= 1; ++dx) {
        int xx = xw + dx;
        if (xx < 0 || xx >= 56) continue;
        short8 vv = *(const short8*)&in[((size_t)yy * 56 + xx) * M_ + mo];
        const int tap = (dy + 1) * 3 + (dx + 1);
#pragma unroll
        for (int q = 0; q < 8; ++q)
          acc[q] += bf2f((u16)vv[q]) * wo[tap * 8 + q];
      }
    }
    u16 res[8];
#pragma unroll
    for (int q = 0; q < 8; ++q) res[q] = f2bf(fmaxf(acc[q], 0.f));
    *(short8*)&out[((size_t)y * 56 + xw) * M_ + mo] = *(const short8*)res;
  }
}

// ---------------- project GEMM + bias + BN3(folded) + residual, fp32 out
__global__ __launch_bounds__(256) void k_proj(
    const u16* __restrict__ h2, const u16* __restrict__ Wk2_t,
    const float* __restrict__ bias3p, const float* __restrict__ xres,
    float* __restrict__ outp) {
  __shared__ __align__(16) u16 As[64][104];  // 64 rows x 96 k
  __shared__ __align__(16) u16 Bs[96][104];  // 96 cols x 96 k
  int b = blockIdx.z, pt = blockIdx.x;
  int p0 = pt * 64;
  int t = threadIdx.x;
  const u16* A = h2 + ((size_t)b * P_ + p0) * M_;
  const u16* Bt = Wk2_t + (size_t)b * F_ * M_;
  int lane = t & 63, w = t >> 6;
  int rA = w * 16 + (lane & 15);
  int k0 = (lane >> 4) * 8;
  f32x4 acc[6] = {};
  for (int kc = 0; kc < 4; ++kc) {
    if (kc) __syncthreads();
#pragma unroll
    for (int j = 0; j < 3; ++j) {
      int ch = t + 256 * j;
      int r = ch / 12, o = (ch % 12) * 8;
      *(short8*)&As[r][o] = *(const short8*)&A[(size_t)r * M_ + kc * 96 + o];
    }
#pragma unroll
    for (int j = 0; j < 5; ++j) {
      int ch = t + 256 * j;
      if (ch < 96 * 12) {
        int r = ch / 12, o = (ch % 12) * 8;
        *(short8*)&Bs[r][o] = *(const short8*)&Bt[(size_t)r * M_ + kc * 96 + o];
      }
    }
    __syncthreads();
#pragma unroll
    for (int ks = 0; ks < 3; ++ks) {
      bf16x8 a = *(const bf16x8*)&As[rA][ks * 32 + k0];
#pragma unroll
      for (int ct = 0; ct < 6; ++ct) {
        bf16x8 bb = *(const bf16x8*)&Bs[ct * 16 + (lane & 15)][ks * 32 + k0];
        acc[ct] = __builtin_amdgcn_mfma_f32_16x16x32_bf16(a, bb, acc[ct], 0, 0, 0);
      }
    }
  }
  const float* xr = xres + (size_t)b * P_ * F_;
  float* op = outp + (size_t)b * P_ * F_;
  int rowb = p0 + w * 16 + (lane >> 4) * 4;
#pragma unroll
  for (int ct = 0; ct < 6; ++ct) {
    int f = ct * 16 + (lane & 15);
    float bias = bias3p[b * F_ + f];
#pragma unroll
    for (int i = 0; i < 4; ++i) {
      size_t idx = (size_t)(rowb + i) * F_ + f;
      op[idx] = acc[ct][i] + bias + xr[idx];
    }
  }
}

extern "C" void kernel_launch(void* const* d_in, const int* in_sizes, int n_in,
                              void* d_out, int out_size, void* d_ws, size_t ws_size,
                              hipStream_t stream) {
  (void)in_sizes; (void)n_in; (void)out_size; (void)ws_size;
  const float* x    = (const float*)d_in[0];
  const float* Wr   = (const float*)d_in[1];
  const float* br   = (const float*)d_in[2];
  const float* Wpw  = (const float*)d_in[3];
  const float* bpw  = (const float*)d_in[4];
  const float* Wdw  = (const float*)d_in[5];
  const float* bdw  = (const float*)d_in[6];
  const float* Wpwl = (const float*)d_in[7];
  const float* bpwl = (const float*)d_in[8];
  const float* g1 = (const float*)d_in[9];
  const float* b1 = (const float*)d_in[10];
  const float* m1 = (const float*)d_in[11];
  const float* v1 = (const float*)d_in[12];
  const float* g2 = (const float*)d_in[13];
  const float* b2 = (const float*)d_in[14];
  const float* m2 = (const float*)d_in[15];
  const float* v2 = (const float*)d_in[16];
  const float* g3 = (const float*)d_in[17];
  const float* b3 = (const float*)d_in[18];
  const float* m3 = (const float*)d_in[19];
  const float* v3 = (const float*)d_in[20];
  float* out = (float*)d_out;

  char* p = (char*)d_ws;
  auto alloc = [&](size_t bytes) {
    char* r = p;
    p += (bytes + 255) & ~(size_t)255;
    return r;
  };
  float* rw     = (float*)alloc((size_t)B_ * E_ * 4);
  u16*   xbf    = (u16*)  alloc((size_t)B_ * P_ * C_ * 2);
  u16*   Wk_t   = (u16*)  alloc((size_t)B_ * M_ * C_ * 2);
  float* bias1p = (float*)alloc((size_t)B_ * M_ * 4);
  float* Wdwf_t = (float*)alloc((size_t)B_ * 48 * 10 * 8 * 4);
  u16*   Wk2_t  = (u16*)  alloc((size_t)B_ * F_ * M_ * 2);
  float* bias3p = (float*)alloc((size_t)B_ * F_ * 4);
  u16*   h1     = (u16*)  alloc((size_t)B_ * P_ * M_ * 2);
  u16*   h2     = (u16*)  alloc((size_t)B_ * P_ * M_ * 2);

  k_routing<<<B_, 384, 0, stream>>>(x, Wr, br, rw, xbf);
  k_mkw1<<<B_, 384, 0, stream>>>(Wpw, bpw, rw, g1, b1, m1, v1, Wk_t, bias1p);
  k_mkdw<<<B_, 384, 0, stream>>>(Wdw, bdw, rw, g2, b2, m2, v2, Wdwf_t);
  k_mkw2<<<B_, 384, 0, stream>>>(Wpwl, bpwl, rw, g3, b3, m3, v3, Wk2_t, bias3p);
  k_expand<<<dim3(49, 6, B_), 256, 0, stream>>>(xbf, Wk_t, bias1p, h1);
  k_dw<<<dim3(56, B_), 256, 0, stream>>>(h1, Wdwf_t, h2);
  k_proj<<<dim3(49, 1, B_), 256, 0, stream>>>(h2, Wk2_t, bias3p, x, out);
}

// Round 2
// 307.425 us; speedup vs baseline: 1.7035x; 1.7035x over previous
//
#include <hip/hip_runtime.h>

#define B_ 32
#define HH 56
#define WW 56
#define C_ 96
#define E_ 4
#define M_ 384
#define F_ 96
#define P_ 3136
#define EPS 1e-3f

typedef __attribute__((ext_vector_type(8))) __bf16 bf16x8;
typedef __attribute__((ext_vector_type(8))) short short8;
typedef __attribute__((ext_vector_type(4))) float f32x4;
typedef __attribute__((ext_vector_type(4))) unsigned short us4;
typedef unsigned short u16;

__device__ __forceinline__ float bf2f(u16 s) {
  union { unsigned u; float f; } c;
  c.u = ((unsigned)s) << 16;
  return c.f;
}
__device__ __forceinline__ u16 f2bf(float f) {
  union { float f; unsigned u; } c;
  c.f = f;
  unsigned u = c.u + 0x7FFFu + ((c.u >> 16) & 1u);
  return (u16)(u >> 16);
}

// ---------------- wide: x -> bf16 + per-chunk partial channel sums
// grid (64 chunks, B), 256 threads; chunk = 49 positions x 96 ch
__global__ __launch_bounds__(256) void k_pool_convert(
    const float* __restrict__ x, float* __restrict__ partial, u16* __restrict__ xbf) {
  int chunk = blockIdx.x, b = blockIdx.y;
  int p0 = chunk * 49;
  const float* xb = x + ((size_t)b * P_ + p0) * C_;
  u16* xo = xbf + ((size_t)b * P_ + p0) * C_;
  int t = threadIdx.x;
  int c4 = t % 24, s = t / 24;  // 24 float4-columns; s in 0..10 (s<10 active)
  __shared__ f32x4 part[10][24];
  if (s < 10) {
    f32x4 sum = {0.f, 0.f, 0.f, 0.f};
    for (int p = s; p < 49; p += 10) {
      f32x4 v = *(const f32x4*)&xb[(size_t)p * C_ + c4 * 4];
      sum += v;
      us4 o;
      o.x = f2bf(v.x); o.y = f2bf(v.y); o.z = f2bf(v.z); o.w = f2bf(v.w);
      *(us4*)&xo[(size_t)p * C_ + c4 * 4] = o;
    }
    part[s][c4] = sum;
  }
  __syncthreads();
  if (s == 0) {
    f32x4 acc = part[0][c4];
#pragma unroll
    for (int ss = 1; ss < 10; ++ss) acc += part[ss][c4];
    *(f32x4*)&partial[(((size_t)b * 64 + chunk)) * C_ + c4 * 4] = acc;
  }
}

// ---------------- finish pooling + dense + sigmoid
__global__ __launch_bounds__(128) void k_routing2(
    const float* __restrict__ partial, const float* __restrict__ Wr,
    const float* __restrict__ br, float* __restrict__ rw) {
  int b = blockIdx.x;
  int c = threadIdx.x;
  __shared__ float pooled[C_];
  if (c < C_) {
    float s = 0.f;
    for (int ch = 0; ch < 64; ++ch) s += partial[((size_t)b * 64 + ch) * C_ + c];
    pooled[c] = s * (1.f / (float)P_);
  }
  __syncthreads();
  if (c < E_) {
    float acc = br[c];
    for (int cc = 0; cc < C_; ++cc) acc += pooled[cc] * Wr[cc * E_ + c];
    rw[b * E_ + c] = 1.f / (1.f + expf(-acc));
  }
}

// ---------------- combine expand weights: Wk_t[b][m][c] (bf16, BN1-folded), bias1p[b][m]
__global__ __launch_bounds__(384) void k_mkw1(
    const float* __restrict__ Wpw, const float* __restrict__ bpw,
    const float* __restrict__ rw,
    const float* __restrict__ g1, const float* __restrict__ b1,
    const float* __restrict__ m1, const float* __restrict__ v1,
    u16* __restrict__ Wk_t, float* __restrict__ bias1p) {
  int b = blockIdx.x;
  float r0 = rw[b * 4 + 0], r1 = rw[b * 4 + 1], r2 = rw[b * 4 + 2], r3 = rw[b * 4 + 3];
  int m = threadIdx.x;  // 384 threads, one per m
  float s1 = g1[m] * rsqrtf(v1[m] + EPS);
  for (int c = 0; c < C_; ++c) {
    float w = r0 * Wpw[(0 * C_ + c) * M_ + m] + r1 * Wpw[(1 * C_ + c) * M_ + m] +
              r2 * Wpw[(2 * C_ + c) * M_ + m] + r3 * Wpw[(3 * C_ + c) * M_ + m];
    Wk_t[((size_t)b * M_ + m) * C_ + c] = f2bf(w * s1);
  }
  float bias = r0 * bpw[0 * M_ + m] + r1 * bpw[1 * M_ + m] + r2 * bpw[2 * M_ + m] + r3 * bpw[3 * M_ + m];
  bias1p[b * M_ + m] = (bias - m1[m]) * s1 + b1[m];
}

// ---------------- combine depthwise weights: Wdwf_t[b][oct][tap0..8 | 9=bias][8] fp32, BN2-folded
__global__ __launch_bounds__(384) void k_mkdw(
    const float* __restrict__ Wdw, const float* __restrict__ bdw,
    const float* __restrict__ rw,
    const float* __restrict__ g2, const float* __restrict__ b2,
    const float* __restrict__ m2, const float* __restrict__ v2,
    float* __restrict__ Wdwf_t) {
  int b = blockIdx.x;
  float r0 = rw[b * 4 + 0], r1 = rw[b * 4 + 1], r2 = rw[b * 4 + 2], r3 = rw[b * 4 + 3];
  int m = threadIdx.x;  // 384
  int oct = m / 8, q = m % 8;
  float s2 = g2[m] * rsqrtf(v2[m] + EPS);
  float* base = Wdwf_t + (((size_t)b * 48 + oct) * 10) * 8;
  for (int tap = 0; tap < 9; ++tap) {
    float w = r0 * Wdw[(0 * 9 + tap) * M_ + m] + r1 * Wdw[(1 * 9 + tap) * M_ + m] +
              r2 * Wdw[(2 * 9 + tap) * M_ + m] + r3 * Wdw[(3 * 9 + tap) * M_ + m];
    base[tap * 8 + q] = w * s2;
  }
  float bias = r0 * bdw[0 * M_ + m] + r1 * bdw[1 * M_ + m] + r2 * bdw[2 * M_ + m] + r3 * bdw[3 * M_ + m];
  base[9 * 8 + q] = (bias - m2[m]) * s2 + b2[m];
}

// ---------------- combine project weights: Wk2_t[b][f][m] (bf16, BN3-folded), bias3p[b][f]
__global__ __launch_bounds__(384) void k_mkw2(
    const float* __restrict__ Wpwl, const float* __restrict__ bpwl,
    const float* __restrict__ rw,
    const float* __restrict__ g3, const float* __restrict__ b3,
    const float* __restrict__ m3, const float* __restrict__ v3,
    u16* __restrict__ Wk2_t, float* __restrict__ bias3p) {
  int b = blockIdx.x;
  float r0 = rw[b * 4 + 0], r1 = rw[b * 4 + 1], r2 = rw[b * 4 + 2], r3 = rw[b * 4 + 3];
  int f = threadIdx.x % F_, s = threadIdx.x / F_;
  float s3 = g3[f] * rsqrtf(v3[f] + EPS);
  for (int m = s; m < M_; m += 4) {
    float w = r0 * Wpwl[(0 * M_ + m) * F_ + f] + r1 * Wpwl[(1 * M_ + m) * F_ + f] +
              r2 * Wpwl[(2 * M_ + m) * F_ + f] + r3 * Wpwl[(3 * M_ + m) * F_ + f];
    Wk2_t[((size_t)b * F_ + f) * M_ + m] = f2bf(w * s3);
  }
  if (s == 0) {
    float bias = r0 * bpwl[0 * F_ + f] + r1 * bpwl[1 * F_ + f] + r2 * bpwl[2 * F_ + f] + r3 * bpwl[3 * F_ + f];
    bias3p[b * F_ + f] = (bias - m3[f]) * s3 + b3[f];
  }
}

// ---------------- expand GEMM: h1[b][p][m] = relu(x_bf[p][:] @ Wk_t[m][:] + bias1p)  (bf16 out)
__global__ __launch_bounds__(256) void k_expand(
    const u16* __restrict__ xbf, const u16* __restrict__ Wk_t,
    const float* __restrict__ bias1p, u16* __restrict__ h1) {
  __shared__ __align__(16) u16 As[64][104];  // 64 rows x 96 k (+8 pad)
  __shared__ __align__(16) u16 Bs[64][104];  // 64 cols x 96 k
  int b = blockIdx.z, pt = blockIdx.x, nt = blockIdx.y;
  int p0 = pt * 64, n0 = nt * 64;
  int t = threadIdx.x;
  const u16* A = xbf + ((size_t)b * P_ + p0) * C_;
  const u16* Bt = Wk_t + ((size_t)b * M_ + n0) * C_;
#pragma unroll
  for (int j = 0; j < 3; ++j) {
    int ch = t + 256 * j;
    int r = ch / 12, o = (ch % 12) * 8;
    *(short8*)&As[r][o] = *(const short8*)&A[(size_t)r * C_ + o];
    *(short8*)&Bs[r][o] = *(const short8*)&Bt[(size_t)r * C_ + o];
  }
  __syncthreads();
  int lane = t & 63, w = t >> 6;
  int rA = w * 16 + (lane & 15);
  int k0 = (lane >> 4) * 8;
  f32x4 acc[4] = {};
#pragma unroll
  for (int kc = 0; kc < 3; ++kc) {
    bf16x8 a = *(const bf16x8*)&As[rA][kc * 32 + k0];
#pragma unroll
    for (int ct = 0; ct < 4; ++ct) {
      bf16x8 bb = *(const bf16x8*)&Bs[ct * 16 + (lane & 15)][kc * 32 + k0];
      acc[ct] = __builtin_amdgcn_mfma_f32_16x16x32_bf16(a, bb, acc[ct], 0, 0, 0);
    }
  }
  u16* out = h1 + (size_t)b * P_ * M_;
  int rowb = p0 + w * 16 + (lane >> 4) * 4;
#pragma unroll
  for (int ct = 0; ct < 4; ++ct) {
    int m = n0 + ct * 16 + (lane & 15);
    float bias = bias1p[b * M_ + m];
#pragma unroll
    for (int i = 0; i < 4; ++i) {
      float v = fmaxf(acc[ct][i] + bias, 0.f);
      out[(size_t)(rowb + i) * M_ + m] = f2bf(v);
    }
  }
}

// ---------------- depthwise 3x3 (SAME, zero pad) + BN2 + relu, bf16 in/out
__global__ __launch_bounds__(256) void k_dw(
    const u16* __restrict__ h1, const float* __restrict__ Wdwf_t,
    u16* __restrict__ h2) {
  int y = blockIdx.x, b = blockIdx.y;
  const u16* in = h1 + (size_t)b * P_ * M_;
  u16* out = h2 + (size_t)b * P_ * M_;
  const float* wb = Wdwf_t + (size_t)b * 48 * 10 * 8;
  for (int task = threadIdx.x; task < 56 * 48; task += 256) {
    int xw = task / 48, oct = task % 48;
    int mo = oct * 8;
    const float* wo = wb + oct * 80;
    float acc[8];
#pragma unroll
    for (int q = 0; q < 8; ++q) acc[q] = wo[72 + q];  // bias slot
#pragma unroll
    for (int dy = -1; dy <= 1; ++dy) {
      int yy = y + dy;
      if (yy < 0 || yy >= 56) continue;
#pragma unroll
      for (int dx = -1; dx <= 1; ++dx) {
        int xx = xw + dx;
        if (xx < 0 || xx >= 56) continue;
        short8 vv = *(const short8*)&in[((size_t)yy * 56 + xx) * M_ + mo];
        const int tap = (dy + 1) * 3 + (dx + 1);
#pragma unroll
        for (int q = 0; q < 8; ++q)
          acc[q] += bf2f((u16)vv[q]) * wo[tap * 8 + q];
      }
    }
    u16 res[8];
#pragma unroll
    for (int q = 0; q < 8; ++q) res[q] = f2bf(fmaxf(acc[q], 0.f));
    *(short8*)&out[((size_t)y * 56 + xw) * M_ + mo] = *(const short8*)res;
  }
}

// ---------------- project GEMM + bias + BN3(folded) + residual, fp32 out
__global__ __launch_bounds__(256) void k_proj(
    const u16* __restrict__ h2, const u16* __restrict__ Wk2_t,
    const float* __restrict__ bias3p, const float* __restrict__ xres,
    float* __restrict__ outp) {
  __shared__ __align__(16) u16 As[64][104];  // 64 rows x 96 k
  __shared__ __align__(16) u16 Bs[96][104];  // 96 cols x 96 k
  int b = blockIdx.z, pt = blockIdx.x;
  int p0 = pt * 64;
  int t = threadIdx.x;
  const u16* A = h2 + ((size_t)b * P_ + p0) * M_;
  const u16* Bt = Wk2_t + (size_t)b * F_ * M_;
  int lane = t & 63, w = t >> 6;
  int rA = w * 16 + (lane & 15);
  int k0 = (lane >> 4) * 8;
  f32x4 acc[6] = {};
  for (int kc = 0; kc < 4; ++kc) {
    if (kc) __syncthreads();
#pragma unroll
    for (int j = 0; j < 3; ++j) {
      int ch = t + 256 * j;
      int r = ch / 12, o = (ch % 12) * 8;
      *(short8*)&As[r][o] = *(const short8*)&A[(size_t)r * M_ + kc * 96 + o];
    }
#pragma unroll
    for (int j = 0; j < 5; ++j) {
      int ch = t + 256 * j;
      if (ch < 96 * 12) {
        int r = ch / 12, o = (ch % 12) * 8;
        *(short8*)&Bs[r][o] = *(const short8*)&Bt[(size_t)r * M_ + kc * 96 + o];
      }
    }
    __syncthreads();
#pragma unroll
    for (int ks = 0; ks < 3; ++ks) {
      bf16x8 a = *(const bf16x8*)&As[rA][ks * 32 + k0];
#pragma unroll
      for (int ct = 0; ct < 6; ++ct) {
        bf16x8 bb = *(const bf16x8*)&Bs[ct * 16 + (lane & 15)][ks * 32 + k0];
        acc[ct] = __builtin_amdgcn_mfma_f32_16x16x32_bf16(a, bb, acc[ct], 0, 0, 0);
      }
    }
  }
  const float* xr = xres + (size_t)b * P_ * F_;
  float* op = outp + (size_t)b * P_ * F_;
  int rowb = p0 + w * 16 + (lane >> 4) * 4;
#pragma unroll
  for (int ct = 0; ct < 6; ++ct) {
    int f = ct * 16 + (lane & 15);
    float bias = bias3p[b * F_ + f];
#pragma unroll
    for (int i = 0; i < 4; ++i) {
      size_t idx = (size_t)(rowb + i) * F_ + f;
      op[idx] = acc[ct][i] + bias + xr[idx];
    }
  }
}

extern "C" void kernel_launch(void* const* d_in, const int* in_sizes, int n_in,
                              void* d_out, int out_size, void* d_ws, size_t ws_size,
                              hipStream_t stream) {
  (void)in_sizes; (void)n_in; (void)out_size; (void)ws_size;
  const float* x    = (const float*)d_in[0];
  const float* Wr   = (const float*)d_in[1];
  const float* br   = (const float*)d_in[2];
  const float* Wpw  = (const float*)d_in[3];
  const float* bpw  = (const float*)d_in[4];
  const float* Wdw  = (const float*)d_in[5];
  const float* bdw  = (const float*)d_in[6];
  const float* Wpwl = (const float*)d_in[7];
  const float* bpwl = (const float*)d_in[8];
  const float* g1 = (const float*)d_in[9];
  const float* b1 = (const float*)d_in[10];
  const float* m1 = (const float*)d_in[11];
  const float* v1 = (const float*)d_in[12];
  const float* g2 = (const float*)d_in[13];
  const float* b2 = (const float*)d_in[14];
  const float* m2 = (const float*)d_in[15];
  const float* v2 = (const float*)d_in[16];
  const float* g3 = (const float*)d_in[17];
  const float* b3 = (const float*)d_in[18];
  const float* m3 = (const float*)d_in[19];
  const float* v3 = (const float*)d_in[20];
  float* out = (float*)d_out;

  char* p = (char*)d_ws;
  auto alloc = [&](size_t bytes) {
    char* r = p;
    p += (bytes + 255) & ~(size_t)255;
    return r;
  };
  float* rw      = (float*)alloc((size_t)B_ * E_ * 4);
  float* partial = (float*)alloc((size_t)B_ * 64 * C_ * 4);
  u16*   xbf     = (u16*)  alloc((size_t)B_ * P_ * C_ * 2);
  u16*   Wk_t    = (u16*)  alloc((size_t)B_ * M_ * C_ * 2);
  float* bias1p  = (float*)alloc((size_t)B_ * M_ * 4);
  float* Wdwf_t  = (float*)alloc((size_t)B_ * 48 * 10 * 8 * 4);
  u16*   Wk2_t   = (u16*)  alloc((size_t)B_ * F_ * M_ * 2);
  float* bias3p  = (float*)alloc((size_t)B_ * F_ * 4);
  u16*   h1      = (u16*)  alloc((size_t)B_ * P_ * M_ * 2);
  u16*   h2      = (u16*)  alloc((size_t)B_ * P_ * M_ * 2);

  k_pool_convert<<<dim3(64, B_), 256, 0, stream>>>(x, partial, xbf);
  k_routing2<<<B_, 128, 0, stream>>>(partial, Wr, br, rw);
  k_mkw1<<<B_, 384, 0, stream>>>(Wpw, bpw, rw, g1, b1, m1, v1, Wk_t, bias1p);
  k_mkdw<<<B_, 384, 0, stream>>>(Wdw, bdw, rw, g2, b2, m2, v2, Wdwf_t);
  k_mkw2<<<B_, 384, 0, stream>>>(Wpwl, bpwl, rw, g3, b3, m3, v3, Wk2_t, bias3p);
  k_expand<<<dim3(49, 6, B_), 256, 0, stream>>>(xbf, Wk_t, bias1p, h1);
  k_dw<<<dim3(56, B_), 256, 0, stream>>>(h1, Wdwf_t, h2);
  k_proj<<<dim3(49, 1, B_), 256, 0, stream>>>(h2, Wk2_t, bias3p, x, out);
}

// Round 3
// 189.309 us; speedup vs baseline: 2.7664x; 1.6239x over previous
//
#include <hip/hip_runtime.h>

#define B_ 32
#define HH 56
#define WW 56
#define C_ 96
#define E_ 4
#define M_ 384
#define F_ 96
#define P_ 3136
#define EPS 1e-3f

typedef __attribute__((ext_vector_type(8))) __bf16 bf16x8;
typedef __attribute__((ext_vector_type(8))) short short8;
typedef __attribute__((ext_vector_type(4))) float f32x4;
typedef __attribute__((ext_vector_type(4))) unsigned short us4;
typedef unsigned short u16;

__device__ __forceinline__ float bf2f(u16 s) {
  union { unsigned u; float f; } c;
  c.u = ((unsigned)s) << 16;
  return c.f;
}
__device__ __forceinline__ u16 f2bf(float f) {
  union { float f; unsigned u; } c;
  c.f = f;
  unsigned u = c.u + 0x7FFFu + ((c.u >> 16) & 1u);
  return (u16)(u >> 16);
}

// ---------------- wide: x -> bf16 + per-chunk partial channel sums
__global__ __launch_bounds__(256) void k_pool_convert(
    const float* __restrict__ x, float* __restrict__ partial, u16* __restrict__ xbf) {
  int chunk = blockIdx.x, b = blockIdx.y;
  int p0 = chunk * 49;
  const float* xb = x + ((size_t)b * P_ + p0) * C_;
  u16* xo = xbf + ((size_t)b * P_ + p0) * C_;
  int t = threadIdx.x;
  int c4 = t % 24, s = t / 24;  // 24 float4-columns; s in 0..10 (s<10 active)
  __shared__ f32x4 part[10][24];
  if (s < 10) {
    f32x4 sum = {0.f, 0.f, 0.f, 0.f};
    for (int p = s; p < 49; p += 10) {
      f32x4 v = *(const f32x4*)&xb[(size_t)p * C_ + c4 * 4];
      sum += v;
      us4 o;
      o.x = f2bf(v.x); o.y = f2bf(v.y); o.z = f2bf(v.z); o.w = f2bf(v.w);
      *(us4*)&xo[(size_t)p * C_ + c4 * 4] = o;
    }
    part[s][c4] = sum;
  }
  __syncthreads();
  if (s == 0) {
    f32x4 acc = part[0][c4];
#pragma unroll
    for (int ss = 1; ss < 10; ++ss) acc += part[ss][c4];
    *(f32x4*)&partial[(((size_t)b * 64 + chunk)) * C_ + c4 * 4] = acc;
  }
}

// ---------------- finish pooling + dense + sigmoid
__global__ __launch_bounds__(128) void k_routing2(
    const float* __restrict__ partial, const float* __restrict__ Wr,
    const float* __restrict__ br, float* __restrict__ rw) {
  int b = blockIdx.x;
  int c = threadIdx.x;
  __shared__ float pooled[C_];
  if (c < C_) {
    float s = 0.f;
    for (int ch = 0; ch < 64; ++ch) s += partial[((size_t)b * 64 + ch) * C_ + c];
    pooled[c] = s * (1.f / (float)P_);
  }
  __syncthreads();
  if (c < E_) {
    float acc = br[c];
    for (int cc = 0; cc < C_; ++cc) acc += pooled[cc] * Wr[cc * E_ + c];
    rw[b * E_ + c] = 1.f / (1.f + expf(-acc));
  }
}

// ---------------- combine expand weights: Wk_t[b][m][c] (bf16, BN1-folded), bias1p[b][m]
__global__ __launch_bounds__(384) void k_mkw1(
    const float* __restrict__ Wpw, const float* __restrict__ bpw,
    const float* __restrict__ rw,
    const float* __restrict__ g1, const float* __restrict__ b1,
    const float* __restrict__ m1, const float* __restrict__ v1,
    u16* __restrict__ Wk_t, float* __restrict__ bias1p) {
  int b = blockIdx.x;
  float r0 = rw[b * 4 + 0], r1 = rw[b * 4 + 1], r2 = rw[b * 4 + 2], r3 = rw[b * 4 + 3];
  int m = threadIdx.x;  // 384 threads, one per m
  float s1 = g1[m] * rsqrtf(v1[m] + EPS);
  for (int c = 0; c < C_; ++c) {
    float w = r0 * Wpw[(0 * C_ + c) * M_ + m] + r1 * Wpw[(1 * C_ + c) * M_ + m] +
              r2 * Wpw[(2 * C_ + c) * M_ + m] + r3 * Wpw[(3 * C_ + c) * M_ + m];
    Wk_t[((size_t)b * M_ + m) * C_ + c] = f2bf(w * s1);
  }
  float bias = r0 * bpw[0 * M_ + m] + r1 * bpw[1 * M_ + m] + r2 * bpw[2 * M_ + m] + r3 * bpw[3 * M_ + m];
  bias1p[b * M_ + m] = (bias - m1[m]) * s1 + b1[m];
}

// ---------------- combine depthwise weights: Wdwf_t[b][oct][tap0..8 | 9=bias][8] fp32, BN2-folded
__global__ __launch_bounds__(384) void k_mkdw(
    const float* __restrict__ Wdw, const float* __restrict__ bdw,
    const float* __restrict__ rw,
    const float* __restrict__ g2, const float* __restrict__ b2,
    const float* __restrict__ m2, const float* __restrict__ v2,
    float* __restrict__ Wdwf_t) {
  int b = blockIdx.x;
  float r0 = rw[b * 4 + 0], r1 = rw[b * 4 + 1], r2 = rw[b * 4 + 2], r3 = rw[b * 4 + 3];
  int m = threadIdx.x;  // 384
  int oct = m / 8, q = m % 8;
  float s2 = g2[m] * rsqrtf(v2[m] + EPS);
  float* base = Wdwf_t + (((size_t)b * 48 + oct) * 10) * 8;
  for (int tap = 0; tap < 9; ++tap) {
    float w = r0 * Wdw[(0 * 9 + tap) * M_ + m] + r1 * Wdw[(1 * 9 + tap) * M_ + m] +
              r2 * Wdw[(2 * 9 + tap) * M_ + m] + r3 * Wdw[(3 * 9 + tap) * M_ + m];
    base[tap * 8 + q] = w * s2;
  }
  float bias = r0 * bdw[0 * M_ + m] + r1 * bdw[1 * M_ + m] + r2 * bdw[2 * M_ + m] + r3 * bdw[3 * M_ + m];
  base[9 * 8 + q] = (bias - m2[m]) * s2 + b2[m];
}

// ---------------- combine project weights: Wk2_t[b][f][m] (bf16, BN3-folded), bias3p[b][f]
__global__ __launch_bounds__(384) void k_mkw2(
    const float* __restrict__ Wpwl, const float* __restrict__ bpwl,
    const float* __restrict__ rw,
    const float* __restrict__ g3, const float* __restrict__ b3,
    const float* __restrict__ m3, const float* __restrict__ v3,
    u16* __restrict__ Wk2_t, float* __restrict__ bias3p) {
  int b = blockIdx.x;
  float r0 = rw[b * 4 + 0], r1 = rw[b * 4 + 1], r2 = rw[b * 4 + 2], r3 = rw[b * 4 + 3];
  int f = threadIdx.x % F_, s = threadIdx.x / F_;
  float s3 = g3[f] * rsqrtf(v3[f] + EPS);
  for (int m = s; m < M_; m += 4) {
    float w = r0 * Wpwl[(0 * M_ + m) * F_ + f] + r1 * Wpwl[(1 * M_ + m) * F_ + f] +
              r2 * Wpwl[(2 * M_ + m) * F_ + f] + r3 * Wpwl[(3 * M_ + m) * F_ + f];
    Wk2_t[((size_t)b * F_ + f) * M_ + m] = f2bf(w * s3);
  }
  if (s == 0) {
    float bias = r0 * bpwl[0 * F_ + f] + r1 * bpwl[1 * F_ + f] + r2 * bpwl[2 * F_ + f] + r3 * bpwl[3 * F_ + f];
    bias3p[b * F_ + f] = (bias - m3[f]) * s3 + b3[f];
  }
}

// ---------------- expand GEMM: h1[b][p][m] = relu(x_bf[p][:] @ Wk_t[m][:] + bias1p)  (bf16 out)
__global__ __launch_bounds__(256) void k_expand(
    const u16* __restrict__ xbf, const u16* __restrict__ Wk_t,
    const float* __restrict__ bias1p, u16* __restrict__ h1) {
  __shared__ __align__(16) u16 As[64][104];  // 64 rows x 96 k (+8 pad)
  __shared__ __align__(16) u16 Bs[64][104];  // 64 cols x 96 k
  int b = blockIdx.z, pt = blockIdx.x, nt = blockIdx.y;
  int p0 = pt * 64, n0 = nt * 64;
  int t = threadIdx.x;
  const u16* A = xbf + ((size_t)b * P_ + p0) * C_;
  const u16* Bt = Wk_t + ((size_t)b * M_ + n0) * C_;
#pragma unroll
  for (int j = 0; j < 3; ++j) {
    int ch = t + 256 * j;
    int r = ch / 12, o = (ch % 12) * 8;
    *(short8*)&As[r][o] = *(const short8*)&A[(size_t)r * C_ + o];
    *(short8*)&Bs[r][o] = *(const short8*)&Bt[(size_t)r * C_ + o];
  }
  __syncthreads();
  int lane = t & 63, w = t >> 6;
  int rA = w * 16 + (lane & 15);
  int k0 = (lane >> 4) * 8;
  f32x4 acc[4] = {};
#pragma unroll
  for (int kc = 0; kc < 3; ++kc) {
    bf16x8 a = *(const bf16x8*)&As[rA][kc * 32 + k0];
#pragma unroll
    for (int ct = 0; ct < 4; ++ct) {
      bf16x8 bb = *(const bf16x8*)&Bs[ct * 16 + (lane & 15)][kc * 32 + k0];
      acc[ct] = __builtin_amdgcn_mfma_f32_16x16x32_bf16(a, bb, acc[ct], 0, 0, 0);
    }
  }
  u16* out = h1 + (size_t)b * P_ * M_;
  int rowb = p0 + w * 16 + (lane >> 4) * 4;
#pragma unroll
  for (int ct = 0; ct < 4; ++ct) {
    int m = n0 + ct * 16 + (lane & 15);
    float bias = bias1p[b * M_ + m];
#pragma unroll
    for (int i = 0; i < 4; ++i) {
      float v = fmaxf(acc[ct][i] + bias, 0.f);
      out[(size_t)(rowb + i) * M_ + m] = f2bf(v);
    }
  }
}

// ---------------- depthwise 3x3 (SAME) + BN2 + relu, bf16 in/out
// thread owns fixed (x, oct): weights in registers, iterate 14 rows of y
__global__ __launch_bounds__(384) void k_dw(
    const u16* __restrict__ h1, const float* __restrict__ Wdwf_t,
    u16* __restrict__ h2) {
  int b = blockIdx.z;
  int t = blockIdx.x * 384 + threadIdx.x;   // 0..2687
  int xw = t / 48, oct = t % 48;
  int y0 = blockIdx.y * 14;
  int mo = oct * 8;

  const float* wo = Wdwf_t + ((size_t)b * 48 + oct) * 80;
  float wreg[9][8];
  float bias[8];
#pragma unroll
  for (int i = 0; i < 18; ++i)
    ((f32x4*)&wreg[0][0])[i] = *(const f32x4*)&wo[i * 4];
  *(f32x4*)&bias[0] = *(const f32x4*)&wo[72];
  *(f32x4*)&bias[4] = *(const f32x4*)&wo[76];

  const u16* in = h1 + (size_t)b * P_ * M_;
  u16* out = h2 + (size_t)b * P_ * M_;

  for (int y = y0; y < y0 + 14; ++y) {
    float acc[8];
#pragma unroll
    for (int q = 0; q < 8; ++q) acc[q] = bias[q];
#pragma unroll
    for (int dy = 0; dy < 3; ++dy) {
      int yy = y + dy - 1;
      bool rowok = ((unsigned)yy < 56u);
#pragma unroll
      for (int dx = 0; dx < 3; ++dx) {
        int xx = xw + dx - 1;
        bool ok = rowok && ((unsigned)xx < 56u);
        short8 v = {0, 0, 0, 0, 0, 0, 0, 0};
        if (ok) v = *(const short8*)&in[((size_t)yy * 56 + xx) * M_ + mo];
#pragma unroll
        for (int q = 0; q < 8; ++q)
          acc[q] += bf2f((u16)v[q]) * wreg[dy * 3 + dx][q];
      }
    }
    u16 res[8];
#pragma unroll
    for (int q = 0; q < 8; ++q) res[q] = f2bf(fmaxf(acc[q], 0.f));
    *(short8*)&out[((size_t)y * 56 + xw) * M_ + mo] = *(const short8*)res;
  }
}

// ---------------- project GEMM + bias + BN3(folded) + residual, fp32 out
__global__ __launch_bounds__(256) void k_proj(
    const u16* __restrict__ h2, const u16* __restrict__ Wk2_t,
    const float* __restrict__ bias3p, const float* __restrict__ xres,
    float* __restrict__ outp) {
  __shared__ __align__(16) u16 As[64][104];  // 64 rows x 96 k
  __shared__ __align__(16) u16 Bs[96][104];  // 96 cols x 96 k
  int b = blockIdx.z, pt = blockIdx.x;
  int p0 = pt * 64;
  int t = threadIdx.x;
  const u16* A = h2 + ((size_t)b * P_ + p0) * M_;
  const u16* Bt = Wk2_t + (size_t)b * F_ * M_;
  int lane = t & 63, w = t >> 6;
  int rA = w * 16 + (lane & 15);
  int k0 = (lane >> 4) * 8;
  f32x4 acc[6] = {};
  for (int kc = 0; kc < 4; ++kc) {
    if (kc) __syncthreads();
#pragma unroll
    for (int j = 0; j < 3; ++j) {
      int ch = t + 256 * j;
      int r = ch / 12, o = (ch % 12) * 8;
      *(short8*)&As[r][o] = *(const short8*)&A[(size_t)r * M_ + kc * 96 + o];
    }
#pragma unroll
    for (int j = 0; j < 5; ++j) {
      int ch = t + 256 * j;
      if (ch < 96 * 12) {
        int r = ch / 12, o = (ch % 12) * 8;
        *(short8*)&Bs[r][o] = *(const short8*)&Bt[(size_t)r * M_ + kc * 96 + o];
      }
    }
    __syncthreads();
#pragma unroll
    for (int ks = 0; ks < 3; ++ks) {
      bf16x8 a = *(const bf16x8*)&As[rA][ks * 32 + k0];
#pragma unroll
      for (int ct = 0; ct < 6; ++ct) {
        bf16x8 bb = *(const bf16x8*)&Bs[ct * 16 + (lane & 15)][ks * 32 + k0];
        acc[ct] = __builtin_amdgcn_mfma_f32_16x16x32_bf16(a, bb, acc[ct], 0, 0, 0);
      }
    }
  }
  const float* xr = xres + (size_t)b * P_ * F_;
  float* op = outp + (size_t)b * P_ * F_;
  int rowb = p0 + w * 16 + (lane >> 4) * 4;
#pragma unroll
  for (int ct = 0; ct < 6; ++ct) {
    int f = ct * 16 + (lane & 15);
    float bias = bias3p[b * F_ + f];
#pragma unroll
    for (int i = 0; i < 4; ++i) {
      size_t idx = (size_t)(rowb + i) * F_ + f;
      op[idx] = acc[ct][i] + bias + xr[idx];
    }
  }
}

extern "C" void kernel_launch(void* const* d_in, const int* in_sizes, int n_in,
                              void* d_out, int out_size, void* d_ws, size_t ws_size,
                              hipStream_t stream) {
  (void)in_sizes; (void)n_in; (void)out_size; (void)ws_size;
  const float* x    = (const float*)d_in[0];
  const float* Wr   = (const float*)d_in[1];
  const float* br   = (const float*)d_in[2];
  const float* Wpw  = (const float*)d_in[3];
  const float* bpw  = (const float*)d_in[4];
  const float* Wdw  = (const float*)d_in[5];
  const float* bdw  = (const float*)d_in[6];
  const float* Wpwl = (const float*)d_in[7];
  const float* bpwl = (const float*)d_in[8];
  const float* g1 = (const float*)d_in[9];
  const float* b1 = (const float*)d_in[10];
  const float* m1 = (const float*)d_in[11];
  const float* v1 = (const float*)d_in[12];
  const float* g2 = (const float*)d_in[13];
  const float* b2 = (const float*)d_in[14];
  const float* m2 = (const float*)d_in[15];
  const float* v2 = (const float*)d_in[16];
  const float* g3 = (const float*)d_in[17];
  const float* b3 = (const float*)d_in[18];
  const float* m3 = (const float*)d_in[19];
  const float* v3 = (const float*)d_in[20];
  float* out = (float*)d_out;

  char* p = (char*)d_ws;
  auto alloc = [&](size_t bytes) {
    char* r = p;
    p += (bytes + 255) & ~(size_t)255;
    return r;
  };
  float* rw      = (float*)alloc((size_t)B_ * E_ * 4);
  float* partial = (float*)alloc((size_t)B_ * 64 * C_ * 4);
  u16*   xbf     = (u16*)  alloc((size_t)B_ * P_ * C_ * 2);
  u16*   Wk_t    = (u16*)  alloc((size_t)B_ * M_ * C_ * 2);
  float* bias1p  = (float*)alloc((size_t)B_ * M_ * 4);
  float* Wdwf_t  = (float*)alloc((size_t)B_ * 48 * 10 * 8 * 4);
  u16*   Wk2_t   = (u16*)  alloc((size_t)B_ * F_ * M_ * 2);
  float* bias3p  = (float*)alloc((size_t)B_ * F_ * 4);
  u16*   h1      = (u16*)  alloc((size_t)B_ * P_ * M_ * 2);
  u16*   h2      = (u16*)  alloc((size_t)B_ * P_ * M_ * 2);

  k_pool_convert<<<dim3(64, B_), 256, 0, stream>>>(x, partial, xbf);
  k_routing2<<<B_, 128, 0, stream>>>(partial, Wr, br, rw);
  k_mkw1<<<B_, 384, 0, stream>>>(Wpw, bpw, rw, g1, b1, m1, v1, Wk_t, bias1p);
  k_mkdw<<<B_, 384, 0, stream>>>(Wdw, bdw, rw, g2, b2, m2, v2, Wdwf_t);
  k_mkw2<<<B_, 384, 0, stream>>>(Wpwl, bpwl, rw, g3, b3, m3, v3, Wk2_t, bias3p);
  k_expand<<<dim3(49, 6, B_), 256, 0, stream>>>(xbf, Wk_t, bias1p, h1);
  k_dw<<<dim3(7, 4, B_), 384, 0, stream>>>(h1, Wdwf_t, h2);
  k_proj<<<dim3(49, 1, B_), 256, 0, stream>>>(h2, Wk2_t, bias3p, x, out);
}

// Round 4
// 129.070 us; speedup vs baseline: 4.0575x; 1.4667x over previous
//
#include <hip/hip_runtime.h>

#define B_ 32
#define HH 56
#define WW 56
#define C_ 96
#define E_ 4
#define M_ 384
#define F_ 96
#define P_ 3136
#define EPS 1e-3f

typedef __attribute__((ext_vector_type(8))) __bf16 bf16x8;
typedef __attribute__((ext_vector_type(8))) short short8;
typedef __attribute__((ext_vector_type(4))) float f32x4;
typedef __attribute__((ext_vector_type(2))) float f32x2;
typedef __attribute__((ext_vector_type(4))) unsigned short us4;
typedef unsigned short u16;

__device__ __forceinline__ float bf2f(u16 s) {
  union { unsigned u; float f; } c;
  c.u = ((unsigned)s) << 16;
  return c.f;
}
__device__ __forceinline__ u16 f2bf(float f) {
  union { float f; unsigned u; } c;
  c.f = f;
  unsigned u = c.u + 0x7FFFu + ((c.u >> 16) & 1u);
  return (u16)(u >> 16);
}
__device__ __forceinline__ f32x2 bfpair(unsigned u) {
  union { unsigned i; float f; } lo, hi;
  lo.i = u << 16;
  hi.i = u & 0xffff0000u;
  f32x2 r;
  r.x = lo.f;
  r.y = hi.f;
  return r;
}

// ---------------- pooling only (x stays fp32 for expand)
__global__ __launch_bounds__(256) void k_pool(
    const float* __restrict__ x, float* __restrict__ partial) {
  int chunk = blockIdx.x, b = blockIdx.y;
  int p0 = chunk * 49;
  const float* xb = x + ((size_t)b * P_ + p0) * C_;
  int t = threadIdx.x;
  int c4 = t % 24, s = t / 24;
  __shared__ f32x4 part[10][24];
  if (s < 10) {
    f32x4 sum = {0.f, 0.f, 0.f, 0.f};
    for (int p = s; p < 49; p += 10)
      sum += *(const f32x4*)&xb[(size_t)p * C_ + c4 * 4];
    part[s][c4] = sum;
  }
  __syncthreads();
  if (s == 0) {
    f32x4 acc = part[0][c4];
#pragma unroll
    for (int ss = 1; ss < 10; ++ss) acc += part[ss][c4];
    *(f32x4*)&partial[(((size_t)b * 64 + chunk)) * C_ + c4 * 4] = acc;
  }
}

// ---------------- finish pooling + dense + sigmoid
__global__ __launch_bounds__(128) void k_routing2(
    const float* __restrict__ partial, const float* __restrict__ Wr,
    const float* __restrict__ br, float* __restrict__ rw) {
  int b = blockIdx.x;
  int c = threadIdx.x;
  __shared__ float pooled[C_];
  if (c < C_) {
    float s = 0.f;
    for (int ch = 0; ch < 64; ++ch) s += partial[((size_t)b * 64 + ch) * C_ + c];
    pooled[c] = s * (1.f / (float)P_);
  }
  __syncthreads();
  if (c < E_) {
    float acc = br[c];
    for (int cc = 0; cc < C_; ++cc) acc += pooled[cc] * Wr[cc * E_ + c];
    rw[b * E_ + c] = 1.f / (1.f + expf(-acc));
  }
}

// ---------------- all weight combines in one kernel. grid (B_, 13), 256 thr
// seg 0..5 : Wk_t[b][m][c] chunks of 64 m (BN1-folded, bf16)
// seg 6    : Wdwf_t (BN2-folded) + bias1p + bias3p
// seg 7..12: Wk2_t[b][f][m] chunks of 64 m (BN3-folded, bf16)
__global__ __launch_bounds__(256) void k_mkall(
    const float* __restrict__ Wpw, const float* __restrict__ bpw,
    const float* __restrict__ Wdw, const float* __restrict__ bdw,
    const float* __restrict__ Wpwl, const float* __restrict__ bpwl,
    const float* __restrict__ rw,
    const float* __restrict__ g1, const float* __restrict__ b1,
    const float* __restrict__ m1, const float* __restrict__ v1,
    const float* __restrict__ g2, const float* __restrict__ b2,
    const float* __restrict__ m2, const float* __restrict__ v2,
    const float* __restrict__ g3, const float* __restrict__ b3,
    const float* __restrict__ m3, const float* __restrict__ v3,
    u16* __restrict__ Wk_t, float* __restrict__ bias1p,
    float* __restrict__ Wdwf_t,
    u16* __restrict__ Wk2_t, float* __restrict__ bias3p) {
  int b = blockIdx.x, seg = blockIdx.y;
  float r0 = rw[b * 4 + 0], r1 = rw[b * 4 + 1], r2 = rw[b * 4 + 2], r3 = rw[b * 4 + 3];
  int t = threadIdx.x;
  if (seg < 6) {
    __shared__ __align__(16) u16 tile[64][104];
    int ml = t & 63;
    int m = seg * 64 + ml, cp = t >> 6;
    float s1 = g1[m] * rsqrtf(v1[m] + EPS);
#pragma unroll
    for (int j = 0; j < 24; ++j) {
      int c = cp + 4 * j;
      float w = r0 * Wpw[(0 * C_ + c) * M_ + m] + r1 * Wpw[(1 * C_ + c) * M_ + m] +
                r2 * Wpw[(2 * C_ + c) * M_ + m] + r3 * Wpw[(3 * C_ + c) * M_ + m];
      tile[ml][c] = f2bf(w * s1);
    }
    __syncthreads();
    u16* dst = Wk_t + ((size_t)b * M_ + seg * 64) * C_;
#pragma unroll
    for (int k = 0; k < 3; ++k) {
      int ch = t + 256 * k;  // < 768
      int mr = ch / 12, off = (ch % 12) * 8;
      *(short8*)&dst[(size_t)mr * C_ + off] = *(const short8*)&tile[mr][off];
    }
  } else if (seg == 6) {
    for (int m = t; m < M_; m += 256) {
      float s2 = g2[m] * rsqrtf(v2[m] + EPS);
      int oct = m >> 3, q = m & 7;
      float* base = Wdwf_t + ((size_t)b * 48 + oct) * 80;
#pragma unroll
      for (int tap = 0; tap < 9; ++tap) {
        float w = r0 * Wdw[(0 * 9 + tap) * M_ + m] + r1 * Wdw[(1 * 9 + tap) * M_ + m] +
                  r2 * Wdw[(2 * 9 + tap) * M_ + m] + r3 * Wdw[(3 * 9 + tap) * M_ + m];
        base[tap * 8 + q] = w * s2;
      }
      float bias = r0 * bdw[m] + r1 * bdw[M_ + m] + r2 * bdw[2 * M_ + m] + r3 * bdw[3 * M_ + m];
      base[72 + q] = (bias - m2[m]) * s2 + b2[m];
      float s1 = g1[m] * rsqrtf(v1[m] + EPS);
      float bb = r0 * bpw[m] + r1 * bpw[M_ + m] + r2 * bpw[2 * M_ + m] + r3 * bpw[3 * M_ + m];
      bias1p[b * M_ + m] = (bb - m1[m]) * s1 + b1[m];
    }
    if (t < F_) {
      float s3 = g3[t] * rsqrtf(v3[t] + EPS);
      float bb = r0 * bpwl[t] + r1 * bpwl[F_ + t] + r2 * bpwl[2 * F_ + t] + r3 * bpwl[3 * F_ + t];
      bias3p[b * F_ + t] = (bb - m3[t]) * s3 + b3[t];
    }
  } else {
    __shared__ __align__(16) u16 tile2[96][72];
    int m0 = (seg - 7) * 64;
#pragma unroll
    for (int j = 0; j < 24; ++j) {
      int id = t + 256 * j;  // < 6144
      int m = id / 96, f = id % 96;
      float w = r0 * Wpwl[(0 * M_ + m0 + m) * F_ + f] + r1 * Wpwl[(1 * M_ + m0 + m) * F_ + f] +
                r2 * Wpwl[(2 * M_ + m0 + m) * F_ + f] + r3 * Wpwl[(3 * M_ + m0 + m) * F_ + f];
      float s3 = g3[f] * rsqrtf(v3[f] + EPS);
      tile2[f][m] = f2bf(w * s3);
    }
    __syncthreads();
    u16* dst = Wk2_t + (size_t)b * F_ * M_ + m0;
#pragma unroll
    for (int k = 0; k < 3; ++k) {
      int ch = t + 256 * k;  // < 768
      int f = ch / 8, off = (ch % 8) * 8;
      *(short8*)&dst[(size_t)f * M_ + off] = *(const short8*)&tile2[f][off];
    }
  }
}

// ---------------- expand GEMM: reads x fp32 directly; loops all 6 n-tiles
__global__ __launch_bounds__(256) void k_expand(
    const float* __restrict__ x, const u16* __restrict__ Wk_t,
    const float* __restrict__ bias1p, u16* __restrict__ h1) {
  __shared__ __align__(16) u16 As[64][104];
  __shared__ __align__(16) u16 Bs[64][104];
  int pt = blockIdx.x, b = blockIdx.y;
  int p0 = pt * 64;
  int t = threadIdx.x;
  const float* A = x + ((size_t)b * P_ + p0) * C_;
#pragma unroll
  for (int j = 0; j < 6; ++j) {
    int ch = t + 256 * j;  // < 1536
    int r = ch / 24, o = (ch % 24) * 4;
    f32x4 v = *(const f32x4*)&A[(size_t)r * C_ + o];
    unsigned lo_, hi_;
    asm("v_cvt_pk_bf16_f32 %0, %1, %2" : "=v"(lo_) : "v"(v.x), "v"(v.y));
    asm("v_cvt_pk_bf16_f32 %0, %1, %2" : "=v"(hi_) : "v"(v.z), "v"(v.w));
    uint2 st = {lo_, hi_};
    *(uint2*)&As[r][o] = st;
  }
  const u16* Bt = Wk_t + (size_t)b * M_ * C_;
  u16* out = h1 + (size_t)b * P_ * M_;
  int lane = t & 63, w = t >> 6;
  int rA = w * 16 + (lane & 15);
  int k0 = (lane >> 4) * 8;
  __syncthreads();
  for (int nt = 0; nt < 6; ++nt) {
    if (nt) __syncthreads();
#pragma unroll
    for (int j = 0; j < 3; ++j) {
      int ch = t + 256 * j;
      int r = ch / 12, o = (ch % 12) * 8;
      *(short8*)&Bs[r][o] = *(const short8*)&Bt[((size_t)(nt * 64 + r)) * C_ + o];
    }
    __syncthreads();
    f32x4 acc[4] = {};
#pragma unroll
    for (int kc = 0; kc < 3; ++kc) {
      bf16x8 a = *(const bf16x8*)&As[rA][kc * 32 + k0];
#pragma unroll
      for (int ct = 0; ct < 4; ++ct) {
        bf16x8 bb = *(const bf16x8*)&Bs[ct * 16 + (lane & 15)][kc * 32 + k0];
        acc[ct] = __builtin_amdgcn_mfma_f32_16x16x32_bf16(a, bb, acc[ct], 0, 0, 0);
      }
    }
    int rowb = p0 + w * 16 + (lane >> 4) * 4;
    int n0 = nt * 64;
#pragma unroll
    for (int ct = 0; ct < 4; ++ct) {
      int m = n0 + ct * 16 + (lane & 15);
      float bias = bias1p[b * M_ + m];
#pragma unroll
      for (int i = 0; i < 4; ++i) {
        float v = fmaxf(acc[ct][i] + bias, 0.f);
        out[(size_t)(rowb + i) * M_ + m] = f2bf(v);
      }
    }
  }
}

// ---------------- depthwise 3x3 + BN2 + relu, sliding-window registers
// thread owns (xw, oct); 4-row rotating window; 7 output rows per strip
struct Row { f32x2 v[3][4]; };
__global__ __launch_bounds__(128) void k_dw(
    const u16* __restrict__ h1, const float* __restrict__ Wdwf_t,
    u16* __restrict__ h2) {
  int b = blockIdx.z;
  int t = blockIdx.x * 128 + threadIdx.x;  // 0..2687
  int xw = t / 48, oct = t % 48;
  int y0 = blockIdx.y * 7;
  const float* wo = Wdwf_t + ((size_t)b * 48 + oct) * 80;
  f32x2 w2[40];
#pragma unroll
  for (int i = 0; i < 40; ++i) w2[i] = *(const f32x2*)&wo[i * 2];
  const u16* inp = h1 + (size_t)b * P_ * M_ + oct * 8;
  u16* outp = h2 + (size_t)b * P_ * M_ + oct * 8;

  auto loadr = [&](Row& r, int yy) {
    bool rowok = ((unsigned)yy < 56u);
#pragma unroll
    for (int dx = 0; dx < 3; ++dx) {
      int xx = xw + dx - 1;
      uint4 u = {0u, 0u, 0u, 0u};
      if (rowok && ((unsigned)xx < 56u))
        u = *(const uint4*)&inp[((size_t)yy * 56 + xx) * M_];
      r.v[dx][0] = bfpair(u.x);
      r.v[dx][1] = bfpair(u.y);
      r.v[dx][2] = bfpair(u.z);
      r.v[dx][3] = bfpair(u.w);
    }
  };
  auto comp = [&](int y, const Row& A, const Row& B, const Row& C) {
    f32x2 acc[4];
#pragma unroll
    for (int j = 0; j < 4; ++j) acc[j] = w2[36 + j];  // bias
#pragma unroll
    for (int dx = 0; dx < 3; ++dx) {
#pragma unroll
      for (int j = 0; j < 4; ++j) {
        acc[j] += A.v[dx][j] * w2[(0 + dx) * 4 + j];
        acc[j] += B.v[dx][j] * w2[(3 + dx) * 4 + j];
        acc[j] += C.v[dx][j] * w2[(6 + dx) * 4 + j];
      }
    }
    unsigned o[4];
#pragma unroll
    for (int j = 0; j < 4; ++j) {
      float lo = fmaxf(acc[j].x, 0.f), hi = fmaxf(acc[j].y, 0.f);
      asm("v_cvt_pk_bf16_f32 %0, %1, %2" : "=v"(o[j]) : "v"(lo), "v"(hi));
    }
    uint4 st = {o[0], o[1], o[2], o[3]};
    *(uint4*)&outp[((size_t)y * 56 + xw) * M_] = st;
  };

  Row ra, rb, rc, rd;
  loadr(ra, y0 - 1);
  loadr(rb, y0);
  loadr(rc, y0 + 1);
  loadr(rd, y0 + 2);
  comp(y0 + 0, ra, rb, rc);
  loadr(ra, y0 + 3);
  comp(y0 + 1, rb, rc, rd);
  loadr(rb, y0 + 4);
  comp(y0 + 2, rc, rd, ra);
  loadr(rc, y0 + 5);
  comp(y0 + 3, rd, ra, rb);
  loadr(rd, y0 + 6);
  comp(y0 + 4, ra, rb, rc);
  loadr(ra, y0 + 7);
  comp(y0 + 5, rb, rc, rd);
  comp(y0 + 6, rc, rd, ra);
}

// ---------------- project GEMM + bias + BN3(folded) + residual, fp32 out
__global__ __launch_bounds__(256) void k_proj(
    const u16* __restrict__ h2, const u16* __restrict__ Wk2_t,
    const float* __restrict__ bias3p, const float* __restrict__ xres,
    float* __restrict__ outp) {
  __shared__ __align__(16) u16 As[64][104];
  __shared__ __align__(16) u16 Bs[96][104];
  int b = blockIdx.z, pt = blockIdx.x;
  int p0 = pt * 64;
  int t = threadIdx.x;
  const u16* A = h2 + ((size_t)b * P_ + p0) * M_;
  const u16* Bt = Wk2_t + (size_t)b * F_ * M_;
  int lane = t & 63, w = t >> 6;
  int rA = w * 16 + (lane & 15);
  int k0 = (lane >> 4) * 8;
  f32x4 acc[6] = {};
  for (int kc = 0; kc < 4; ++kc) {
    if (kc) __syncthreads();
#pragma unroll
    for (int j = 0; j < 3; ++j) {
      int ch = t + 256 * j;
      int r = ch / 12, o = (ch % 12) * 8;
      *(short8*)&As[r][o] = *(const short8*)&A[(size_t)r * M_ + kc * 96 + o];
    }
#pragma unroll
    for (int j = 0; j < 5; ++j) {
      int ch = t + 256 * j;
      if (ch < 96 * 12) {
        int r = ch / 12, o = (ch % 12) * 8;
        *(short8*)&Bs[r][o] = *(const short8*)&Bt[(size_t)r * M_ + kc * 96 + o];
      }
    }
    __syncthreads();
#pragma unroll
    for (int ks = 0; ks < 3; ++ks) {
      bf16x8 a = *(const bf16x8*)&As[rA][ks * 32 + k0];
#pragma unroll
      for (int ct = 0; ct < 6; ++ct) {
        bf16x8 bb = *(const bf16x8*)&Bs[ct * 16 + (lane & 15)][ks * 32 + k0];
        acc[ct] = __builtin_amdgcn_mfma_f32_16x16x32_bf16(a, bb, acc[ct], 0, 0, 0);
      }
    }
  }
  const float* xr = xres + (size_t)b * P_ * F_;
  float* op = outp + (size_t)b * P_ * F_;
  int rowb = p0 + w * 16 + (lane >> 4) * 4;
#pragma unroll
  for (int ct = 0; ct < 6; ++ct) {
    int f = ct * 16 + (lane & 15);
    float bias = bias3p[b * F_ + f];
#pragma unroll
    for (int i = 0; i < 4; ++i) {
      size_t idx = (size_t)(rowb + i) * F_ + f;
      op[idx] = acc[ct][i] + bias + xr[idx];
    }
  }
}

extern "C" void kernel_launch(void* const* d_in, const int* in_sizes, int n_in,
                              void* d_out, int out_size, void* d_ws, size_t ws_size,
                              hipStream_t stream) {
  (void)in_sizes; (void)n_in; (void)out_size; (void)ws_size;
  const float* x    = (const float*)d_in[0];
  const float* Wr   = (const float*)d_in[1];
  const float* br   = (const float*)d_in[2];
  const float* Wpw  = (const float*)d_in[3];
  const float* bpw  = (const float*)d_in[4];
  const float* Wdw  = (const float*)d_in[5];
  const float* bdw  = (const float*)d_in[6];
  const float* Wpwl = (const float*)d_in[7];
  const float* bpwl = (const float*)d_in[8];
  const float* g1 = (const float*)d_in[9];
  const float* b1 = (const float*)d_in[10];
  const float* m1 = (const float*)d_in[11];
  const float* v1 = (const float*)d_in[12];
  const float* g2 = (const float*)d_in[13];
  const float* b2 = (const float*)d_in[14];
  const float* m2 = (const float*)d_in[15];
  const float* v2 = (const float*)d_in[16];
  const float* g3 = (const float*)d_in[17];
  const float* b3 = (const float*)d_in[18];
  const float* m3 = (const float*)d_in[19];
  const float* v3 = (const float*)d_in[20];
  float* out = (float*)d_out;

  char* p = (char*)d_ws;
  auto alloc = [&](size_t bytes) {
    char* r = p;
    p += (bytes + 255) & ~(size_t)255;
    return r;
  };
  float* rw      = (float*)alloc((size_t)B_ * E_ * 4);
  float* partial = (float*)alloc((size_t)B_ * 64 * C_ * 4);
  u16*   Wk_t    = (u16*)  alloc((size_t)B_ * M_ * C_ * 2);
  float* bias1p  = (float*)alloc((size_t)B_ * M_ * 4);
  float* Wdwf_t  = (float*)alloc((size_t)B_ * 48 * 10 * 8 * 4);
  u16*   Wk2_t   = (u16*)  alloc((size_t)B_ * F_ * M_ * 2);
  float* bias3p  = (float*)alloc((size_t)B_ * F_ * 4);
  u16*   h1      = (u16*)  alloc((size_t)B_ * P_ * M_ * 2);
  u16*   h2      = (u16*)  alloc((size_t)B_ * P_ * M_ * 2);

  k_pool<<<dim3(64, B_), 256, 0, stream>>>(x, partial);
  k_routing2<<<B_, 128, 0, stream>>>(partial, Wr, br, rw);
  k_mkall<<<dim3(B_, 13), 256, 0, stream>>>(Wpw, bpw, Wdw, bdw, Wpwl, bpwl, rw,
                                            g1, b1, m1, v1, g2, b2, m2, v2,
                                            g3, b3, m3, v3,
                                            Wk_t, bias1p, Wdwf_t, Wk2_t, bias3p);
  k_expand<<<dim3(49, B_), 256, 0, stream>>>(x, Wk_t, bias1p, h1);
  k_dw<<<dim3(21, 8, B_), 128, 0, stream>>>(h1, Wdwf_t, h2);
  k_proj<<<dim3(49, 1, B_), 256, 0, stream>>>(h2, Wk2_t, bias3p, x, out);
}